// Round 1
// baseline (209.702 us; speedup 1.0000x reference)
//
#include <hip/hip_runtime.h>
#include <math.h>

// Problem constants (fixed by setup_inputs)
constexpr int NB = 2;     // batch
constexpr int NC = 2;     // channels
constexpr int NT = 500;   // time
constexpr int NF = 129;   // freq
constexpr int NH = 16;    // heads
constexpr int ND = 100;   // delay

// ------------------------- Kernel 1: V -------------------------
// V[b,h,t,d] = sum_f Q[b,h,t,f] * K[b,h,t+d-(ND-1),f]
// Reparam u = t + d - (ND-1): banded outer product in (t,u) space.
constexpr int TT    = 28;                      // t-tile
constexpr int NTILE = (NT + TT - 1) / TT;      // 18
constexpr int KU    = 128;                     // staged K rows (u = 0..127)
constexpr int QR    = 32;                      // staged Q rows
constexpr int LSTR  = 134;                     // LDS row stride in floats (134 mod 32 = 6 -> <=2-way)
constexpr size_t VSMEM = (size_t)(KU + QR) * LSTR * sizeof(float);  // 85,760 B

__global__ __launch_bounds__(256) void v_kernel(
    const float* __restrict__ x_mic, const float* __restrict__ x_ref,
    const float* __restrict__ w_mic, const float* __restrict__ b_mic,
    const float* __restrict__ w_ref, const float* __restrict__ b_ref,
    float* __restrict__ V)
{
    extern __shared__ float smem[];
    float* Klds = smem;                 // [KU][LSTR]
    float* Qlds = smem + KU * LSTR;     // [QR][LSTR]

    const int tile = blockIdx.x % NTILE;
    const int bh   = blockIdx.x / NTILE;
    const int h = bh % NH, b = bh / NH;
    const int ts = tile * TT;
    const int tid = threadIdx.x;

    const float wm0 = w_mic[h*NC+0], wm1 = w_mic[h*NC+1], bm = b_mic[h];
    const float wr0 = w_ref[h*NC+0], wr1 = w_ref[h*NC+1], br = b_ref[h];

    const float* xm0 = x_mic + ((size_t)b*NC + 0) * NT * NF;
    const float* xm1 = x_mic + ((size_t)b*NC + 1) * NT * NF;
    const float* xr0 = x_ref + ((size_t)b*NC + 0) * NT * NF;
    const float* xr1 = x_ref + ((size_t)b*NC + 1) * NT * NF;

    // Stage K rows: global K row = ts - (ND-1) + row; fuse the ref projection.
    for (int idx = tid; idx < KU * LSTR; idx += 256) {
        int row = idx / LSTR, col = idx - row * LSTR;
        int kr = ts - (ND - 1) + row;
        float v = 0.f;
        if (col < NF && kr >= 0 && kr < NT) {
            int g = kr * NF + col;
            v = wr0 * xr0[g] + wr1 * xr1[g] + br;
        }
        Klds[idx] = v;
    }
    // Stage Q rows (zero-fill pad cols and out-of-range t)
    for (int idx = tid; idx < QR * LSTR; idx += 256) {
        int row = idx / LSTR, col = idx - row * LSTR;
        int qr = ts + row;
        float v = 0.f;
        if (col < NF && qr < NT) {
            int g = qr * NF + col;
            v = wm0 * xm0[g] + wm1 * xm1[g] + bm;
        }
        Qlds[idx] = v;
    }
    __syncthreads();

    const int tx = tid & 31;   // u lane: u = tx + 32*i
    const int ty = tid >> 5;   // t lane: t = ty + 8*j

    float acc[4][4];
    #pragma unroll
    for (int j = 0; j < 4; ++j)
        #pragma unroll
        for (int i = 0; i < 4; ++i) acc[j][i] = 0.f;

    for (int fp = 0; fp < LSTR / 2; ++fp) {
        float2 q[4], k[4];
        #pragma unroll
        for (int j = 0; j < 4; ++j)
            q[j] = *(const float2*)&Qlds[(ty + 8*j) * LSTR + 2*fp];
        #pragma unroll
        for (int i = 0; i < 4; ++i)
            k[i] = *(const float2*)&Klds[(tx + 32*i) * LSTR + 2*fp];
        #pragma unroll
        for (int j = 0; j < 4; ++j)
            #pragma unroll
            for (int i = 0; i < 4; ++i)
                acc[j][i] += q[j].x * k[i].x + q[j].y * k[i].y;
    }

    float* Vb = V + (size_t)(b*NH + h) * NT * ND;
    #pragma unroll
    for (int j = 0; j < 4; ++j) {
        int tt = ty + 8*j;
        int t  = ts + tt;
        #pragma unroll
        for (int i = 0; i < 4; ++i) {
            int uu = tx + 32*i;
            int d  = uu - tt;
            if (tt < TT && t < NT && d >= 0 && d < ND)
                Vb[t * ND + d] = acc[j][i];
        }
    }
}

// ------------------- Kernel 2: conv + softmax -> A -------------------
// A[b,t,d] = softmax_d( sum_{h,kt,kd} V[b,h,t+kt-4,d+kd-1]*w_conv[h,kt,kd] + b_conv )
__global__ __launch_bounds__(128) void cs_kernel(
    const float* __restrict__ V, const float* __restrict__ w_conv,
    const float* __restrict__ b_conv, float* __restrict__ A)
{
    const int t = blockIdx.x % NT;
    const int b = blockIdx.x / NT;
    const int tid = threadIdx.x;
    const int d = tid;

    float s = 0.f;
    if (d < ND) {
        for (int h = 0; h < NH; ++h) {
            const float* Vb = V + (size_t)(b*NH + h) * NT * ND;
            #pragma unroll
            for (int kt = 0; kt < 5; ++kt) {
                int tt = t + kt - 4;
                if (tt < 0) continue;
                const float* vr = Vb + tt * ND;
                const float* w  = w_conv + h*15 + kt*3;
                float vm = (d >= 1)     ? vr[d-1] : 0.f;
                float v0 = vr[d];
                float vp = (d + 1 < ND) ? vr[d+1] : 0.f;
                s += w[0]*vm + w[1]*v0 + w[2]*vp;
            }
        }
        s += b_conv[0];
    }

    // softmax over d (two waves)
    __shared__ float red[4];
    float m = (d < ND) ? s : -3.0e38f;
    #pragma unroll
    for (int o = 32; o > 0; o >>= 1) m = fmaxf(m, __shfl_down(m, o, 64));
    int wid = tid >> 6;
    if ((tid & 63) == 0) red[wid] = m;
    __syncthreads();
    m = fmaxf(red[0], red[1]);
    float e = (d < ND) ? __expf(s - m) : 0.f;
    float sm = e;
    #pragma unroll
    for (int o = 32; o > 0; o >>= 1) sm += __shfl_down(sm, o, 64);
    if ((tid & 63) == 0) red[2 + wid] = sm;
    __syncthreads();
    sm = red[2] + red[3];
    if (d < ND) A[((size_t)b*NT + t) * ND + d] = e / sm;
}

// ------------------------- Kernel 3: y -------------------------
// y[b,c,t,f] = sum_d x_ref[b,c,t+d-(ND-1),f] * A[b,t,d]
constexpr int TT4   = 8;
constexpr int NT4   = (NT + TT4 - 1) / TT4;   // 63
constexpr int XROWS = TT4 + ND - 1;           // 107
constexpr int XSTR  = NF + 1;                 // 130

__global__ __launch_bounds__(256) void y_kernel(
    const float* __restrict__ x_ref, const float* __restrict__ A,
    float* __restrict__ y)
{
    __shared__ float Xlds[XROWS * XSTR];   // 55.6 KB
    __shared__ float Alds[TT4 * ND];       // 3.2 KB

    const int tile = blockIdx.x % NT4;
    const int bc   = blockIdx.x / NT4;
    const int c = bc % NC, b = bc / NC;
    const int t0 = tile * TT4;
    const int tid = threadIdx.x;

    const float* xr = x_ref + (size_t)(b*NC + c) * NT * NF;
    for (int idx = tid; idx < XROWS * XSTR; idx += 256) {
        int row = idx / XSTR, col = idx - row * XSTR;
        int tr = t0 - (ND - 1) + row;
        Xlds[idx] = (col < NF && tr >= 0 && tr < NT) ? xr[tr * NF + col] : 0.f;
    }
    for (int idx = tid; idx < TT4 * ND; idx += 256) {
        int tl = idx / ND;
        int t  = t0 + tl;
        Alds[idx] = (t < NT) ? A[((size_t)b*NT + t) * ND + (idx - tl*ND)] : 0.f;
    }
    __syncthreads();

    for (int o = tid; o < TT4 * NF; o += 256) {
        int tl = o / NF, f = o - tl * NF;
        int t  = t0 + tl;
        if (t >= NT) continue;
        float acc = 0.f;
        #pragma unroll 4
        for (int d = 0; d < ND; ++d)
            acc += Xlds[(tl + d) * XSTR + f] * Alds[tl * ND + d];
        y[((size_t)(b*NC + c) * NT + t) * NF + f] = acc;
    }
}

// ------------------------- launcher -------------------------
extern "C" void kernel_launch(void* const* d_in, const int* in_sizes, int n_in,
                              void* d_out, int out_size, void* d_ws, size_t ws_size,
                              hipStream_t stream)
{
    const float* x_mic  = (const float*)d_in[0];
    const float* x_ref  = (const float*)d_in[1];
    const float* w_mic  = (const float*)d_in[2];
    const float* b_mic  = (const float*)d_in[3];
    const float* w_ref  = (const float*)d_in[4];
    const float* b_ref  = (const float*)d_in[5];
    const float* w_conv = (const float*)d_in[6];
    const float* b_conv = (const float*)d_in[7];
    // d_in[8] = delay (=100), hardcoded as ND
    float* y = (float*)d_out;

    float* V = (float*)d_ws;                              // NB*NH*NT*ND f32 = 6.4 MB
    float* A = V + (size_t)NB * NH * NT * ND;             // NB*NT*ND f32 = 0.4 MB

    v_kernel<<<dim3(NB * NH * NTILE), dim3(256), VSMEM, stream>>>(
        x_mic, x_ref, w_mic, b_mic, w_ref, b_ref, V);
    cs_kernel<<<dim3(NB * NT), dim3(128), 0, stream>>>(V, w_conv, b_conv, A);
    y_kernel<<<dim3(NB * NC * NT4), dim3(256), 0, stream>>>(x_ref, A, y);
}

// Round 4
// 123.188 us; speedup vs baseline: 1.7023x; 1.7023x over previous
//
#include <hip/hip_runtime.h>
#include <math.h>

// Problem constants (fixed by setup_inputs)
constexpr int NB = 2;     // batch
constexpr int NC = 2;     // channels
constexpr int NT = 500;   // time
constexpr int NF = 129;   // freq
constexpr int NH = 16;    // heads
constexpr int ND = 100;   // delay

// Padded V layout: [NB*NH][NT+4][ND+2] (t-pad 4 front, d-pad 1 each side)
constexpr int VTS = NT + 4;    // 504
constexpr int VDS = ND + 2;    // 102
constexpr size_t VELEMS = (size_t)NB * NH * VTS * VDS;   // 1,645,056 f32 = 6.58 MB

typedef _Float16 f16;
typedef _Float16 f16x4 __attribute__((ext_vector_type(4)));
typedef float    f32x4 __attribute__((ext_vector_type(4)));

// ------------------------- Kernel 1: V via MFMA -------------------------
// V[b,h,t,d] = sum_f Q[t,f]*K[u,f], u = t+d-99. For a 16-t tile the band
// u in [ts-99, ts+15] fits one 128-wide u tile (115 <= 128).
// Block: 256 thr (4 waves). LDS: K rows 0..127 (u = ts-99+r), Q rows 128..143.
constexpr int TT   = 16;
constexpr int NTT  = (NT + TT - 1) / TT;   // 32 -> grid 2*16*32 = 1024
constexpr int LROWS = 144;
constexpr int LSTR  = 148;  // f16; 296 B/row -> bank stride 74 (10r mod 32 distinct for 16 rows)

__global__ __launch_bounds__(256) void v_kernel(
    const float* __restrict__ x_mic, const float* __restrict__ x_ref,
    const float* __restrict__ w_mic, const float* __restrict__ b_mic,
    const float* __restrict__ w_ref, const float* __restrict__ b_ref,
    float* __restrict__ Vp)
{
    __shared__ f16 Lds[LROWS * LSTR];   // 42,624 B -> 3 blocks/CU

    const int tid = threadIdx.x;
    const int tt  = blockIdx.x & 31;
    const int bh  = blockIdx.x >> 5;    // b*NH + h
    const int h = bh & 15, b = bh >> 4;
    const int ts = tt * TT;
    const int US = ts - (ND - 1);       // u of K row 0

    const float wm0 = w_mic[h*NC+0], wm1 = w_mic[h*NC+1], bm = b_mic[h];
    const float wr0 = w_ref[h*NC+0], wr1 = w_ref[h*NC+1], br = b_ref[h];

    const float* xm0 = x_mic + ((size_t)b*NC + 0) * NT * NF;
    const float* xm1 = x_mic + ((size_t)b*NC + 1) * NT * NF;
    const float* xr0 = x_ref + ((size_t)b*NC + 0) * NT * NF;
    const float* xr1 = x_ref + ((size_t)b*NC + 1) * NT * NF;

    const int w = tid >> 6;       // wave id 0..3
    const int l = tid & 63;

    // ---- stage: row r -> K (r<128) or Q (r>=128); lane-per-column, coalesced
    for (int rr = 0; rr < 36; ++rr) {
        const int r = w + 4 * rr;                       // 0..143
        const bool isK = (r < 128);
        const int row = isK ? (US + r) : (ts + r - 128);
        const bool valid = (row >= 0) && (row < NT);
        const float* p0 = isK ? xr0 : xm0;
        const float* p1 = isK ? xr1 : xm1;
        const float w0 = isK ? wr0 : wm0;
        const float w1 = isK ? wr1 : wm1;
        const float bb = isK ? br  : bm;
        const size_t base = (size_t)row * NF;
        f16* ldsrow = Lds + r * LSTR;

        float v0 = 0.f, v1 = 0.f;
        if (valid) {
            v0 = w0 * p0[base + l]      + w1 * p1[base + l]      + bb;
            v1 = w0 * p0[base + l + 64] + w1 * p1[base + l + 64] + bb;
        }
        ldsrow[l]      = (f16)v0;
        ldsrow[l + 64] = (f16)v1;
        if (l < LSTR - 128) {           // cols 128..147 (129th element + zero pad)
            const int c = 128 + l;
            float v2 = (valid && c < NF) ? (w0 * p0[base + c] + w1 * p1[base + c] + bb) : 0.f;
            ldsrow[c] = (f16)v2;
        }
    }
    __syncthreads();

    // ---- MFMA: wave w covers u_loc [32w, 32w+32), M=16 t rows, K=144 (9 steps)
    const int lr = l & 15;
    const int lk = l >> 4;
    f32x4 acc0 = {0.f, 0.f, 0.f, 0.f};
    f32x4 acc1 = {0.f, 0.f, 0.f, 0.f};

    #pragma unroll
    for (int kk = 0; kk < 9; ++kk) {
        const int fo = 16 * kk + 4 * lk;
        f16x4 a  = *(const f16x4*)&Lds[(128 + lr) * LSTR + fo];
        f16x4 b0 = *(const f16x4*)&Lds[(32*w      + lr) * LSTR + fo];
        f16x4 b1 = *(const f16x4*)&Lds[(32*w + 16 + lr) * LSTR + fo];
        acc0 = __builtin_amdgcn_mfma_f32_16x16x16f16(a, b0, acc0, 0, 0, 0);
        acc1 = __builtin_amdgcn_mfma_f32_16x16x16f16(a, b1, acc1, 0, 0, 0);
    }

    // ---- epilogue: D row = t_loc = 4*lk+j, col = u_loc; d = u_loc - t_loc
    float* Vb = Vp + (size_t)bh * VTS * VDS;
    #pragma unroll
    for (int j = 0; j < 4; ++j) {
        const int t_loc = 4 * lk + j;
        const int t_g = ts + t_loc;
        if (t_g < NT) {
            const int u0 = 32*w + lr;
            const int d0 = u0 - t_loc;
            if (d0 >= 0 && d0 < ND) Vb[(size_t)(t_g + 4) * VDS + d0 + 1] = acc0[j];
            const int u1 = u0 + 16;
            const int d1 = u1 - t_loc;
            if (d1 >= 0 && d1 < ND) Vb[(size_t)(t_g + 4) * VDS + d1 + 1] = acc1[j];
        }
    }
}

// ------------------- Kernel 2: conv + softmax -> A -------------------
// Branch-free 240-tap conv from zero-padded V, then 2-wave softmax over d.
__global__ __launch_bounds__(128) void cs_kernel(
    const float* __restrict__ Vp, const float* __restrict__ w_conv,
    const float* __restrict__ b_conv, float* __restrict__ A)
{
    const int t = blockIdx.x % NT;
    const int b = blockIdx.x / NT;
    const int tid = threadIdx.x;
    const int d = tid;

    float s = 0.f;
    if (d < ND) {
        #pragma unroll 4
        for (int h = 0; h < NH; ++h) {
            const float* Vb = Vp + ((size_t)(b*NH + h) * VTS + t) * VDS + d;
            const float* wh = w_conv + h * 15;
            #pragma unroll
            for (int kt = 0; kt < 5; ++kt)
                #pragma unroll
                for (int kd = 0; kd < 3; ++kd)
                    s += wh[kt*3 + kd] * Vb[kt*VDS + kd];
        }
        s += b_conv[0];
    }

    __shared__ float red[4];
    float m = (d < ND) ? s : -3.4e38f;
    #pragma unroll
    for (int o = 32; o > 0; o >>= 1) m = fmaxf(m, __shfl_down(m, o, 64));
    if ((tid & 63) == 0) red[tid >> 6] = m;
    __syncthreads();
    m = fmaxf(red[0], red[1]);
    float e = (d < ND) ? __expf(s - m) : 0.f;
    float sm = e;
    #pragma unroll
    for (int o = 32; o > 0; o >>= 1) sm += __shfl_down(sm, o, 64);
    if ((tid & 63) == 0) red[2 + (tid >> 6)] = sm;
    __syncthreads();
    const float inv = 1.f / (red[2] + red[3]);
    if (d < ND) A[((size_t)b*NT + t) * ND + d] = e * inv;
}

// ------------------------- Kernel 3: y -------------------------
// y[b,c,t,f] = sum_d A[b,t,d] * x_ref[b,c,t+d-99,f]; flat thread per output.
__global__ __launch_bounds__(256) void y_kernel(
    const float* __restrict__ x_ref, const float* __restrict__ A,
    float* __restrict__ y)
{
    const int idx = blockIdx.x * 256 + threadIdx.x;
    if (idx >= NB * NC * NT * NF) return;
    const int f  = idx % NF;
    const int r  = idx / NF;
    const int t  = r % NT;
    const int bc = r / NT;
    const int b  = bc >> 1;

    const float* At = A + ((size_t)b * NT + t) * ND;
    const float* X  = x_ref + (size_t)bc * NT * NF + f;
    const int d0 = (t >= ND - 1) ? 0 : (ND - 1 - t);

    const float* Xp = X + (size_t)(t + d0 - (ND - 1)) * NF;
    float acc = 0.f;
    #pragma unroll 4
    for (int d = d0; d < ND; ++d) {
        acc += At[d] * Xp[0];
        Xp += NF;
    }
    y[idx] = acc;
}

// ------------------------- launcher -------------------------
extern "C" void kernel_launch(void* const* d_in, const int* in_sizes, int n_in,
                              void* d_out, int out_size, void* d_ws, size_t ws_size,
                              hipStream_t stream)
{
    const float* x_mic  = (const float*)d_in[0];
    const float* x_ref  = (const float*)d_in[1];
    const float* w_mic  = (const float*)d_in[2];
    const float* b_mic  = (const float*)d_in[3];
    const float* w_ref  = (const float*)d_in[4];
    const float* b_ref  = (const float*)d_in[5];
    const float* w_conv = (const float*)d_in[6];
    const float* b_conv = (const float*)d_in[7];
    float* y = (float*)d_out;

    float* Vp = (float*)d_ws;                 // padded V, 6.58 MB
    float* A  = Vp + VELEMS;                  // NB*NT*ND f32 = 0.4 MB

    hipMemsetAsync(Vp, 0, VELEMS * sizeof(float), stream);

    v_kernel<<<dim3(NB * NH * NTT), dim3(256), 0, stream>>>(
        x_mic, x_ref, w_mic, b_mic, w_ref, b_ref, Vp);
    cs_kernel<<<dim3(NB * NT), dim3(128), 0, stream>>>(Vp, w_conv, b_conv, A);
    const int nOut = NB * NC * NT * NF;
    y_kernel<<<dim3((nOut + 255) / 256), dim3(256), 0, stream>>>(x_ref, A, y);
}

// Round 5
// 121.048 us; speedup vs baseline: 1.7324x; 1.0177x over previous
//
#include <hip/hip_runtime.h>
#include <math.h>

// Problem constants (fixed by setup_inputs)
constexpr int NB = 2;     // batch
constexpr int NC = 2;     // channels
constexpr int NT = 500;   // time
constexpr int NF = 129;   // freq
constexpr int NH = 16;    // heads
constexpr int ND = 100;   // delay

// Padded V layout: [NB*NH][NT+4][ND+2] (t-pad 4 front, d-pad 1 each side)
constexpr int VTS = NT + 4;    // 504
constexpr int VDS = ND + 2;    // 102
constexpr size_t VELEMS = (size_t)NB * NH * VTS * VDS;   // 6.58 MB

typedef _Float16 f16;
typedef _Float16 f16x4 __attribute__((ext_vector_type(4)));
typedef float    f32x4 __attribute__((ext_vector_type(4)));

// ------------------------- Kernel 1: V via MFMA -------------------------
// V[b,h,t,d] = sum_f Q[t,f]*K[u,f], u = t+d-99. For a 16-t tile the band
// u in [ts-99, ts+15] fits one 128-wide u tile (115 <= 128).
// Also zero-fills all pad cells of Vp it owns (no separate memset).
constexpr int TT   = 16;
constexpr int NTT  = (NT + TT - 1) / TT;   // 32 -> grid 2*16*32 = 1024
constexpr int LROWS = 144;
constexpr int LSTR  = 148;  // f16 row stride

__global__ __launch_bounds__(256) void v_kernel(
    const float* __restrict__ x_mic, const float* __restrict__ x_ref,
    const float* __restrict__ w_mic, const float* __restrict__ b_mic,
    const float* __restrict__ w_ref, const float* __restrict__ b_ref,
    float* __restrict__ Vp)
{
    __shared__ f16 Lds[LROWS * LSTR];   // 42,624 B -> 3 blocks/CU

    const int tid = threadIdx.x;
    const int tt  = blockIdx.x & 31;
    const int bh  = blockIdx.x >> 5;    // b*NH + h
    const int h = bh & 15, b = bh >> 4;
    const int ts = tt * TT;
    const int US = ts - (ND - 1);       // u of K row 0

    const float wm0 = w_mic[h*NC+0], wm1 = w_mic[h*NC+1], bm = b_mic[h];
    const float wr0 = w_ref[h*NC+0], wr1 = w_ref[h*NC+1], br = b_ref[h];

    const float* xm0 = x_mic + ((size_t)b*NC + 0) * NT * NF;
    const float* xm1 = x_mic + ((size_t)b*NC + 1) * NT * NF;
    const float* xr0 = x_ref + ((size_t)b*NC + 0) * NT * NF;
    const float* xr1 = x_ref + ((size_t)b*NC + 1) * NT * NF;

    const int w = tid >> 6;       // wave id 0..3
    const int l = tid & 63;

    // ---- stage: row r -> K (r<128) or Q (r>=128); lane-per-column, coalesced
    for (int rr = 0; rr < 36; ++rr) {
        const int r = w + 4 * rr;                       // 0..143
        const bool isK = (r < 128);
        const int row = isK ? (US + r) : (ts + r - 128);
        const bool valid = (row >= 0) && (row < NT);
        const float* p0 = isK ? xr0 : xm0;
        const float* p1 = isK ? xr1 : xm1;
        const float w0 = isK ? wr0 : wm0;
        const float w1 = isK ? wr1 : wm1;
        const float bb = isK ? br  : bm;
        const size_t base = (size_t)row * NF;
        f16* ldsrow = Lds + r * LSTR;

        float v0 = 0.f, v1 = 0.f;
        if (valid) {
            v0 = w0 * p0[base + l]      + w1 * p1[base + l]      + bb;
            v1 = w0 * p0[base + l + 64] + w1 * p1[base + l + 64] + bb;
        }
        ldsrow[l]      = (f16)v0;
        ldsrow[l + 64] = (f16)v1;
        if (l < LSTR - 128) {           // cols 128..147 (129th element + zero pad)
            const int c = 128 + l;
            float v2 = (valid && c < NF) ? (w0 * p0[base + c] + w1 * p1[base + c] + bb) : 0.f;
            ldsrow[c] = (f16)v2;
        }
    }
    __syncthreads();

    // ---- MFMA: wave w covers u_loc [32w, 32w+32), M=16 t rows, K=144 (9 steps)
    const int lr = l & 15;
    const int lk = l >> 4;
    f32x4 acc0 = {0.f, 0.f, 0.f, 0.f};
    f32x4 acc1 = {0.f, 0.f, 0.f, 0.f};

    #pragma unroll
    for (int kk = 0; kk < 9; ++kk) {
        const int fo = 16 * kk + 4 * lk;
        f16x4 a  = *(const f16x4*)&Lds[(128 + lr) * LSTR + fo];
        f16x4 b0 = *(const f16x4*)&Lds[(32*w      + lr) * LSTR + fo];
        f16x4 b1 = *(const f16x4*)&Lds[(32*w + 16 + lr) * LSTR + fo];
        acc0 = __builtin_amdgcn_mfma_f32_16x16x16f16(a, b0, acc0, 0, 0, 0);
        acc1 = __builtin_amdgcn_mfma_f32_16x16x16f16(a, b1, acc1, 0, 0, 0);
    }

    // ---- epilogue: D row = t_loc = 4*lk+j, col = u_loc; d = u_loc - t_loc
    float* Vb = Vp + (size_t)bh * VTS * VDS;
    #pragma unroll
    for (int j = 0; j < 4; ++j) {
        const int t_loc = 4 * lk + j;
        const int t_g = ts + t_loc;
        if (t_g < NT) {
            const int u0 = 32*w + lr;
            const int d0 = u0 - t_loc;
            if (d0 >= 0 && d0 < ND) Vb[(size_t)(t_g + 4) * VDS + d0 + 1] = acc0[j];
            const int u1 = u0 + 16;
            const int d1 = u1 - t_loc;
            if (d1 >= 0 && d1 < ND) Vb[(size_t)(t_g + 4) * VDS + d1 + 1] = acc1[j];
        }
    }

    // ---- pad zeroing (replaces the global memset):
    // d-pad columns (d'=0 and d'=101) for this block's 16 t-rows
    if (tid < 32) {
        const int rr = tid >> 1, side = tid & 1;
        const int t_g = ts + rr;
        if (t_g < NT)
            Vb[(size_t)(t_g + 4) * VDS + (side ? (VDS - 1) : 0)] = 0.f;
    }
    // front t-halo rows 0..3 (only the tt==0 block for this bh)
    if (tt == 0) {
        for (int q = tid; q < 4 * VDS; q += 256) Vb[q] = 0.f;
    }
}

// ---------------- Kernel 2: conv + softmax + y (fused) ----------------
// Block per (b,t), 256 threads. Phase A: lanes 0..99 do the 240-tap conv
// (branch-free from padded V) + 2-wave softmax -> A in LDS.
// Phase B: all 256 lanes compute y[b, :, t, :] = sum_d A[d]*x_ref[...].
__global__ __launch_bounds__(256) void csy_kernel(
    const float* __restrict__ Vp, const float* __restrict__ w_conv,
    const float* __restrict__ b_conv, const float* __restrict__ x_ref,
    float* __restrict__ y)
{
    const int t = blockIdx.x % NT;
    const int b = blockIdx.x / NT;
    const int tid = threadIdx.x;
    const int d = tid;

    __shared__ float Alds[ND];
    __shared__ float red[4];

    float s = 0.f;
    if (d < ND) {
        #pragma unroll 4
        for (int h = 0; h < NH; ++h) {
            const float* Vb = Vp + ((size_t)(b*NH + h) * VTS + t) * VDS + d;
            const float* wh = w_conv + h * 15;
            #pragma unroll
            for (int kt = 0; kt < 5; ++kt)
                #pragma unroll
                for (int kd = 0; kd < 3; ++kd)
                    s += wh[kt*3 + kd] * Vb[kt*VDS + kd];
        }
        s += b_conv[0];
    }

    // softmax over d across waves 0..1 (lanes 100..127 contribute -inf/0)
    if (tid < 128) {
        float m = (d < ND) ? s : -3.4e38f;
        #pragma unroll
        for (int o = 32; o > 0; o >>= 1) m = fmaxf(m, __shfl_down(m, o, 64));
        if ((tid & 63) == 0) red[tid >> 6] = m;
    }
    __syncthreads();
    const float m = fmaxf(red[0], red[1]);
    const float e = (d < ND) ? __expf(s - m) : 0.f;
    if (tid < 128) {
        float sm = e;
        #pragma unroll
        for (int o = 32; o > 0; o >>= 1) sm += __shfl_down(sm, o, 64);
        if ((tid & 63) == 0) red[2 + (tid >> 6)] = sm;
    }
    __syncthreads();
    const float inv = 1.f / (red[2] + red[3]);
    if (d < ND) Alds[d] = e * inv;
    __syncthreads();

    // Phase B: y[b,c,t,f] = sum_d A[d] * x_ref[b,c,t+d-99,f]
    const int d0 = (t >= ND - 1) ? 0 : (ND - 1 - t);
    for (int o = tid; o < NC * NF; o += 256) {
        const int c = o / NF, f = o - c * NF;
        const float* X = x_ref + ((size_t)(b*NC + c) * NT + (t + d0 - (ND - 1))) * NF + f;
        float acc = 0.f;
        #pragma unroll 4
        for (int dd = d0; dd < ND; ++dd) {
            acc += Alds[dd] * X[0];
            X += NF;
        }
        y[((size_t)(b*NC + c) * NT + t) * NF + f] = acc;
    }
}

// ------------------------- launcher -------------------------
extern "C" void kernel_launch(void* const* d_in, const int* in_sizes, int n_in,
                              void* d_out, int out_size, void* d_ws, size_t ws_size,
                              hipStream_t stream)
{
    const float* x_mic  = (const float*)d_in[0];
    const float* x_ref  = (const float*)d_in[1];
    const float* w_mic  = (const float*)d_in[2];
    const float* b_mic  = (const float*)d_in[3];
    const float* w_ref  = (const float*)d_in[4];
    const float* b_ref  = (const float*)d_in[5];
    const float* w_conv = (const float*)d_in[6];
    const float* b_conv = (const float*)d_in[7];
    float* y = (float*)d_out;

    float* Vp = (float*)d_ws;   // padded V, 6.58 MB (pads zeroed by v_kernel)

    v_kernel<<<dim3(NB * NH * NTT), dim3(256), 0, stream>>>(
        x_mic, x_ref, w_mic, b_mic, w_ref, b_ref, Vp);
    csy_kernel<<<dim3(NB * NT), dim3(256), 0, stream>>>(
        Vp, w_conv, b_conv, x_ref, y);
}

// Round 7
// 108.483 us; speedup vs baseline: 1.9330x; 1.1158x over previous
//
#include <hip/hip_runtime.h>
#include <math.h>

// Problem constants (fixed by setup_inputs)
constexpr int NB = 2;     // batch
constexpr int NC = 2;     // channels
constexpr int NT = 500;   // time
constexpr int NF = 129;   // freq
constexpr int NH = 16;    // heads
constexpr int ND = 100;   // delay

// 9 correlation maps: m = i*3+j, i/j in {xm0, xm1, ones} x {xr0, xr1, ones}
// C_m[b][t][d] = sum_f Xm_i[t,f] * Xr_j[u,f], u = t+d-99 (0 if u<0 via zero-staging)
constexpr int NMAP = 9;
constexpr size_t CSTRIDE = (size_t)NT * ND;            // 50,000 floats per map
constexpr size_t CELEMS  = (size_t)NB * NMAP * CSTRIDE; // 3.6 MB

typedef _Float16 f16;
typedef _Float16 f16x4 __attribute__((ext_vector_type(4)));
typedef float    f32x4 __attribute__((ext_vector_type(4)));

// ------------------------- Kernel 1: correlation maps via MFMA -------------------------
// Block = (b, j, t-tile). Stages ref-side channel j (128 u rows) + all 3 mic-side
// channels (48 t rows) as f16; computes C_{0j},C_{1j},C_{2j} for a 16-t tile.
constexpr int TT    = 16;
constexpr int NTT   = 32;                  // ceil(500/16)
constexpr int BROWS = 128;                 // ref band rows
constexpr int LROWS = 176;                 // + 3*16 mic rows
constexpr int LSTR  = 148;                 // f16 row stride (bank-conflict-free for b64 reads)

__global__ __launch_bounds__(256) void corr_kernel(
    const float* __restrict__ x_mic, const float* __restrict__ x_ref,
    float* __restrict__ C)
{
    __shared__ f16 Lds[LROWS * LSTR];   // 52,096 B -> 3 blocks/CU

    const int tid = threadIdx.x;
    const int tt = blockIdx.x & 31;
    const int bj = blockIdx.x >> 5;     // b*3 + j
    const int j = bj % 3, b = bj / 3;
    const int ts = tt * TT;
    const int US = ts - (ND - 1);       // global u of LDS row 0

    const float* xr = x_ref + (size_t)b * NC * NT * NF;
    const float* xm = x_mic + (size_t)b * NC * NT * NF;

    const int w = tid >> 6;   // wave 0..3
    const int l = tid & 63;

    // ---- stage 176 rows; lane-per-column, coalesced, no divides
    for (int rr = 0; rr < 44; ++rr) {
        const int r = w + 4 * rr;
        f16* row = Lds + r * LSTR;
        float v0 = 0.f, v1 = 0.f, v2 = 0.f;
        if (r < BROWS) {                       // ref side, channel j (ones if j==2)
            const int u = US + r;
            if (u >= 0 && u < NT) {
                if (j < 2) {
                    const float* p = xr + (size_t)j * NT * NF + (size_t)u * NF;
                    v0 = p[l]; v1 = p[l + 64]; if (l == 0) v2 = p[128];
                } else { v0 = 1.f; v1 = 1.f; if (l == 0) v2 = 1.f; }
            }
        } else {                               // mic side, channel i = (r-128)/16
            const int q = r - BROWS;
            const int i = q >> 4;
            const int t = ts + (q & 15);
            if (t < NT) {
                if (i < 2) {
                    const float* p = xm + (size_t)i * NT * NF + (size_t)t * NF;
                    v0 = p[l]; v1 = p[l + 64]; if (l == 0) v2 = p[128];
                } else { v0 = 1.f; v1 = 1.f; if (l == 0) v2 = 1.f; }
            }
        }
        row[l]      = (f16)v0;
        row[l + 64] = (f16)v1;
        if (l < LSTR - 128) row[128 + l] = (l == 0) ? (f16)v2 : (f16)0.f;
    }
    __syncthreads();

    // ---- MFMA: wave w covers u_loc in [32w, 32w+32); 3 mic maps x 2 u-subtiles
    const int lr = l & 15;
    const int lk = l >> 4;
    f32x4 acc[3][2] = {};

    #pragma unroll
    for (int kk = 0; kk < 9; ++kk) {
        const int fo = 16 * kk + 4 * lk;
        f16x4 bf0 = *(const f16x4*)&Lds[(32*w      + lr) * LSTR + fo];
        f16x4 bf1 = *(const f16x4*)&Lds[(32*w + 16 + lr) * LSTR + fo];
        #pragma unroll
        for (int i = 0; i < 3; ++i) {
            f16x4 af = *(const f16x4*)&Lds[(BROWS + 16*i + lr) * LSTR + fo];
            acc[i][0] = __builtin_amdgcn_mfma_f32_16x16x16f16(af, bf0, acc[i][0], 0, 0, 0);
            acc[i][1] = __builtin_amdgcn_mfma_f32_16x16x16f16(af, bf1, acc[i][1], 0, 0, 0);
        }
    }

    // ---- epilogue: D row = t_loc = 4*lk+jj, col = u_loc; d = u_loc - t_loc
    #pragma unroll
    for (int i = 0; i < 3; ++i) {
        float* Cb = C + ((size_t)b * NMAP + (i*3 + j)) * CSTRIDE;
        #pragma unroll
        for (int n = 0; n < 2; ++n) {
            const int u_loc = 32*w + 16*n + lr;
            #pragma unroll
            for (int jj = 0; jj < 4; ++jj) {
                const int t_loc = 4*lk + jj;
                const int t_g = ts + t_loc;
                const int d = u_loc - t_loc;
                if (t_g < NT && d >= 0 && d < ND)
                    Cb[(size_t)t_g * ND + d] = acc[i][n][jj];
            }
        }
    }
}

// ---------------- Kernel 2: folded conv + softmax + y (fused) ----------------
// S[t,d] = b_conv + sum_{tap in bounds} sum_m G[m][tap] * C_m[t', d']
// with G[m=3i+j][tap] = sum_h w_conv[h,tap] * WM(h,i) * WR(h,j), WM(h,2)=b_mic etc.
__global__ __launch_bounds__(256) void csy_kernel(
    const float* __restrict__ C, const float* __restrict__ w_conv,
    const float* __restrict__ b_conv,
    const float* __restrict__ w_mic, const float* __restrict__ b_mic,
    const float* __restrict__ w_ref, const float* __restrict__ b_ref,
    const float* __restrict__ x_ref, float* __restrict__ y)
{
    const int t = blockIdx.x % NT;
    const int b = blockIdx.x / NT;
    const int tid = threadIdx.x;

    __shared__ float G[NMAP][15];
    __shared__ float Alds[ND];
    __shared__ float red[4];

    // folded conv weights (redundant per block; 135 threads x 16-FMA loop)
    if (tid < NMAP * 15) {
        const int m = tid / 15, tap = tid % 15;
        const int i = m / 3, jj = m % 3;
        float s = 0.f;
        for (int h = 0; h < NH; ++h) {
            const float a  = (i  < 2) ? w_mic[h*NC + i]  : b_mic[h];
            const float bb = (jj < 2) ? w_ref[h*NC + jj] : b_ref[h];
            s += w_conv[h*15 + tap] * a * bb;
        }
        G[m][tap] = s;
    }
    __syncthreads();

    const int d = tid;
    float s = 0.f;
    if (d < ND) {
        const float* Cb = C + (size_t)b * NMAP * CSTRIDE;
        #pragma unroll
        for (int kt = 0; kt < 5; ++kt) {
            const int tp = t - 4 + kt;
            if (tp < 0) continue;               // wave-uniform
            #pragma unroll
            for (int kd = 0; kd < 3; ++kd) {
                const int dp = d - 1 + kd;
                if (dp < 0 || dp >= ND) continue;
                const float* p = Cb + (size_t)tp * ND + dp;
                const int tap = kt*3 + kd;
                float a2 = 0.f;
                #pragma unroll
                for (int m = 0; m < NMAP; ++m)
                    a2 += G[m][tap] * p[m * CSTRIDE];
                s += a2;
            }
        }
        s += b_conv[0];
    }

    // softmax over d across waves 0..1
    if (tid < 128) {
        float mx = (d < ND) ? s : -3.4e38f;
        #pragma unroll
        for (int o = 32; o > 0; o >>= 1) mx = fmaxf(mx, __shfl_down(mx, o, 64));
        if ((tid & 63) == 0) red[tid >> 6] = mx;
    }
    __syncthreads();
    const float mx = fmaxf(red[0], red[1]);
    const float e = (d < ND) ? __expf(s - mx) : 0.f;
    if (tid < 128) {
        float sm = e;
        #pragma unroll
        for (int o = 32; o > 0; o >>= 1) sm += __shfl_down(sm, o, 64);
        if ((tid & 63) == 0) red[2 + (tid >> 6)] = sm;
    }
    __syncthreads();
    const float inv = 1.f / (red[2] + red[3]);
    if (d < ND) Alds[d] = e * inv;
    __syncthreads();

    // Phase B: y[b,c,t,f] = sum_d A[d] * x_ref[b,c,t+d-99,f]
    const int d0 = (t >= ND - 1) ? 0 : (ND - 1 - t);
    for (int o = tid; o < NC * NF; o += 256) {
        const int c = o / NF, f = o - c * NF;
        const float* X = x_ref + ((size_t)(b*NC + c) * NT + (t + d0 - (ND - 1))) * NF + f;
        float acc = 0.f;
        #pragma unroll 4
        for (int dd = d0; dd < ND; ++dd) {
            acc += Alds[dd] * X[0];
            X += NF;
        }
        y[((size_t)(b*NC + c) * NT + t) * NF + f] = acc;
    }
}

// ------------------------- launcher -------------------------
extern "C" void kernel_launch(void* const* d_in, const int* in_sizes, int n_in,
                              void* d_out, int out_size, void* d_ws, size_t ws_size,
                              hipStream_t stream)
{
    const float* x_mic  = (const float*)d_in[0];
    const float* x_ref  = (const float*)d_in[1];
    const float* w_mic  = (const float*)d_in[2];
    const float* b_mic  = (const float*)d_in[3];
    const float* w_ref  = (const float*)d_in[4];
    const float* b_ref  = (const float*)d_in[5];
    const float* w_conv = (const float*)d_in[6];
    const float* b_conv = (const float*)d_in[7];
    float* y = (float*)d_out;

    float* C = (float*)d_ws;   // 9 correlation maps, 3.6 MB (all cells written by corr_kernel)

    corr_kernel<<<dim3(NB * 3 * NTT), dim3(256), 0, stream>>>(x_mic, x_ref, C);
    csy_kernel<<<dim3(NB * NT), dim3(256), 0, stream>>>(
        C, w_conv, b_conv, w_mic, b_mic, w_ref, b_ref, x_ref, y);
}